// Round 2
// baseline (776.709 us; speedup 1.0000x reference)
//
#include <hip/hip_runtime.h>
#include <hip/hip_bf16.h>
#include <math.h>

#define BATCH 2
#define SEQ 2048
#define EMBED 1024
#define NHEAD 16
#define QKV_N 3072
#define M_TOK 4096
#define NT_KV (SEQ / 64)
#define OUT_ELEMS ((size_t)M_TOK * EMBED)

typedef __attribute__((ext_vector_type(4))) float f32x4;
typedef __attribute__((ext_vector_type(8))) short bf16x8;

__device__ __forceinline__ short f2bf(float f) {
    __hip_bfloat16 h = __float2bfloat16(f);
    return *reinterpret_cast<short*>(&h);
}
__device__ __forceinline__ float bf2f(short s) {
    union { unsigned u; float f; } c;
    c.u = ((unsigned)(unsigned short)s) << 16;
    return c.f;
}

// async global->LDS, 16B per lane; LDS dest = wave-uniform base + lane*16
__device__ __forceinline__ void gld16(const void* g, void* l) {
    __builtin_amdgcn_global_load_lds(
        (const __attribute__((address_space(1))) unsigned int*)g,
        (__attribute__((address_space(3))) unsigned int*)l, 16, 0, 0);
}

// ---------------------------------------------------------------------------
// fp32 -> bf16 cast, 4 elems/thread
// ---------------------------------------------------------------------------
__global__ __launch_bounds__(256) void cast_bf16_kernel(
    const float* __restrict__ in, short* __restrict__ out, int n4)
{
    int i = blockIdx.x * 256 + threadIdx.x;
    if (i >= n4) return;
    float4 v = ((const float4*)in)[i];
    unsigned long long pk =
        (unsigned long long)(unsigned short)f2bf(v.x)
      | ((unsigned long long)(unsigned short)f2bf(v.y) << 16)
      | ((unsigned long long)(unsigned short)f2bf(v.z) << 32)
      | ((unsigned long long)(unsigned short)f2bf(v.w) << 48);
    ((unsigned long long*)out)[i] = pk;
}

// ---------------------------------------------------------------------------
// Transpose+cast: in[R][C] fp32 -> out[C][R] bf16. 64x64 tiles.
// ---------------------------------------------------------------------------
__global__ __launch_bounds__(256) void transpose_cast_kernel(
    const float* __restrict__ in, short* __restrict__ out, int R, int C)
{
    __shared__ float t[64][65];
    const int r0 = blockIdx.y * 64, c0 = blockIdx.x * 64;
    for (int i = threadIdx.x; i < 4096; i += 256) {
        int r = i >> 6, c = i & 63;
        t[r][c] = in[(size_t)(r0 + r) * C + c0 + c];
    }
    __syncthreads();
    for (int i = threadIdx.x; i < 4096; i += 256) {
        int c = i >> 6, r = i & 63;
        out[(size_t)(c0 + c) * R + r0 + r] = f2bf(t[r][c]);
    }
}

// ---------------------------------------------------------------------------
// Pack V per head, transposed + bank-swizzle baked in:
// Vp[bh][kt][d][key'] tiles of 64x64 bf16, key' = key ^ ((d&7)<<3).
// ---------------------------------------------------------------------------
__global__ __launch_bounds__(256) void pack_v_kernel(
    const short* __restrict__ qkvb, short* __restrict__ Vp)
{
    __shared__ short tv[64][72];
    const int kt = blockIdx.x, bh = blockIdx.y;
    const int b = bh >> 4, h = bh & 15;
    const int t = threadIdx.x;
    const int row = t >> 2, cp = t & 3;
    const short* src = qkvb + (size_t)(b * SEQ + kt * 64 + row) * QKV_N
                       + 2 * EMBED + h * 64 + cp * 16;
    bf16x8 a0 = *(const bf16x8*)src;
    bf16x8 a1 = *(const bf16x8*)(src + 8);
    #pragma unroll
    for (int j = 0; j < 8; ++j) {
        tv[row][cp * 16 + j] = a0[j];
        tv[row][cp * 16 + 8 + j] = a1[j];
    }
    __syncthreads();
    const int d = row;
    short* dst = Vp + ((size_t)bh * NT_KV + kt) * 4096 + d * 64;
    bf16x8 o0, o1;
    #pragma unroll
    for (int j = 0; j < 8; ++j) {
        o0[j] = tv[cp * 16 + j][d];
        o1[j] = tv[cp * 16 + 8 + j][d];
    }
    *(bf16x8*)(dst + (((2 * cp) ^ (d & 7)) << 3)) = o0;
    *(bf16x8*)(dst + (((2 * cp + 1) ^ (d & 7)) << 3)) = o1;
}

// ---------------------------------------------------------------------------
// bf16 MFMA GEMM (m97 structure): C[M][N] = A[M][K] @ Bt[N][K]^T + bias
// ---------------------------------------------------------------------------
template <bool OUT_BF16>
__global__ __launch_bounds__(256) void gemm_mfma_kernel(
    const short* __restrict__ A, const short* __restrict__ Bt,
    const float* __restrict__ bias, void* __restrict__ C,
    int M, int N, int K)
{
    __shared__ short As[128 * 32];
    __shared__ short Bs[128 * 32];
    const int tid = threadIdx.x;
    const int w = tid >> 6, lane = tid & 63;
    const int quad = lane >> 4, lc = lane & 15;
    const int wm = w & 1, wn = w >> 1;
    const int m0 = blockIdx.y * 128, n0 = blockIdx.x * 128;

    f32x4 acc[4][4] = {};

    const int srow = (lane >> 2);
    const int schk = ((lane & 3) ^ (srow & 3)) * 8;

    for (int k0 = 0; k0 < K; k0 += 32) {
        #pragma unroll
        for (int j = 0; j < 2; ++j) {
            int r = w * 32 + j * 16 + srow;
            gld16(A + ((size_t)(m0 + r) * K + k0 + schk), &As[(w * 32 + j * 16) * 32]);
            gld16(Bt + ((size_t)(n0 + r) * K + k0 + schk), &Bs[(w * 32 + j * 16) * 32]);
        }
        __syncthreads();
        bf16x8 af[4], bf[4];
        #pragma unroll
        for (int i = 0; i < 4; ++i)
            af[i] = *(const bf16x8*)&As[(wm * 64 + i * 16 + lc) * 32
                                        + ((quad ^ (lc & 3)) << 3)];
        #pragma unroll
        for (int i = 0; i < 4; ++i)
            bf[i] = *(const bf16x8*)&Bs[(wn * 64 + i * 16 + lc) * 32
                                        + ((quad ^ (lc & 3)) << 3)];
        #pragma unroll
        for (int mi = 0; mi < 4; ++mi)
            #pragma unroll
            for (int ni = 0; ni < 4; ++ni)
                acc[mi][ni] = __builtin_amdgcn_mfma_f32_16x16x32_bf16(
                    af[mi], bf[ni], acc[mi][ni], 0, 0, 0);
        __syncthreads();
    }

    #pragma unroll
    for (int mi = 0; mi < 4; ++mi) {
        int row = m0 + wm * 64 + mi * 16 + quad * 4;
        #pragma unroll
        for (int ni = 0; ni < 4; ++ni) {
            int col = n0 + wn * 64 + ni * 16 + lc;
            float bc = bias[col];
            #pragma unroll
            for (int r = 0; r < 4; ++r) {
                float v = acc[mi][ni][r] + bc;
                if (OUT_BF16)
                    ((short*)C)[(size_t)(row + r) * N + col] = f2bf(v);
                else
                    ((float*)C)[(size_t)(row + r) * N + col] = v;
            }
        }
    }
}

// ---------------------------------------------------------------------------
// Fused causal attention, two-pass flash, v3:
//   - double-buffered K (pass1) and K+V (pass2): prefetch next kt-tile's
//     gld16 BEFORE compute; ONE barrier per iter (was two + full drain).
//   - pass-2 barrier uses counted vmcnt(4): drains the 4 prefetch loads
//     (oldest in queue) while the 4 attw NT-stores stay in flight (T4).
//   - setprio(1) around MFMA clusters (T5, attn-proven).
//   - LDS 40 KB -> exactly 4 blocks/CU; launch_bounds(256,4) pins VGPR<=128
//     so the qt/(NT-1-qt) pairing balance holds.
// ---------------------------------------------------------------------------
__global__ __launch_bounds__(256, 4) void attn_kernel(
    const short* __restrict__ qkvb,   // [4096][3072] bf16
    const short* __restrict__ Vp,     // [32][32][64][64] bf16, transposed+swz
    float* __restrict__ attw,         // [32][2048][2048]
    short* __restrict__ attb)         // [4096][1024] bf16
{
    const int NT = NT_KV;
    const int qt = (blockIdx.y & 8) ? (NT - 1 - (int)blockIdx.x) : (int)blockIdx.x;
    const int bh = blockIdx.y;
    const int b = bh >> 4, h = bh & 15;
    const int tid = threadIdx.x;
    const int w = tid >> 6, lane = tid & 63;
    const int quad = lane >> 4, lc = lane & 15;
    const int qloc = w * 16 + quad * 4;

    __shared__ short Kb[2][64 * 64];   // [key][d'], d' chunk-swizzled
    __shared__ short Vt[2][64 * 64];   // [d][key'], key' chunk-swizzled
    __shared__ short Ps[4][16 * 64];   // per-wave P [q][key'], swizzled

    // Q fragments, held in registers for both passes
    const short* qptr = qkvb + (size_t)(b * SEQ + qt * 64 + w * 16 + lc) * QKV_N
                        + h * 64 + quad * 8;
    const bf16x8 qf0 = *(const bf16x8*)qptr;
    const bf16x8 qf1 = *(const bf16x8*)(qptr + 32);

    const int srow = lane >> 3;                 // 0..7, row within 8-row chunk
    const int schk = ((lane & 7) ^ srow) * 8;   // swizzled source chunk

    // staging bases (this wave stages rows w*16 .. w*16+15)
    const short* kg0 = qkvb + (size_t)(b * SEQ + w * 16 + srow) * QKV_N
                       + EMBED + h * 64 + schk;
    const size_t kstep = (size_t)64 * QKV_N;
    const short* vg0 = Vp + (size_t)bh * NT * 4096 + (w * 16) * 64 + lane * 8;

    auto stage_k = [&](int kt, int bi) {
        gld16(kg0 + (size_t)kt * kstep, &Kb[bi][(w * 16) * 64]);
        gld16(kg0 + (size_t)kt * kstep + (size_t)8 * QKV_N, &Kb[bi][(w * 16 + 8) * 64]);
    };
    auto stage_v = [&](int kt, int bi) {
        gld16(vg0 + (size_t)kt * 4096, &Vt[bi][(w * 16) * 64]);
        gld16(vg0 + (size_t)kt * 4096 + 512, &Vt[bi][(w * 16 + 8) * 64]);
    };

    float m_i[4], l_i[4];
    #pragma unroll
    for (int r = 0; r < 4; ++r) { m_i[r] = -INFINITY; l_i[r] = 0.f; }

    // ---------------- pass 1: row max & sum ----------------
    int buf = 0;
    stage_k(0, 0);
    __syncthreads();
    for (int kt = 0; kt <= qt; ++kt) {
        if (kt < qt) stage_k(kt + 1, buf ^ 1);
        const bool diag = (kt == qt);
        const short* kb = Kb[buf];
        float sv[4][4];
        __builtin_amdgcn_s_setprio(1);
        #pragma unroll
        for (int ni = 0; ni < 4; ++ni) {
            const int key = ni * 16 + lc;
            f32x4 acc = {};
            bf16x8 kf0 = *(const bf16x8*)&kb[key * 64 + ((quad ^ (key & 7)) << 3)];
            bf16x8 kf1 = *(const bf16x8*)&kb[key * 64 + (((quad | 4) ^ (key & 7)) << 3)];
            acc = __builtin_amdgcn_mfma_f32_16x16x32_bf16(qf0, kf0, acc, 0, 0, 0);
            acc = __builtin_amdgcn_mfma_f32_16x16x32_bf16(qf1, kf1, acc, 0, 0, 0);
            #pragma unroll
            for (int r = 0; r < 4; ++r) {
                float v = acc[r] * 0.125f;
                if (diag && key > (qloc + r)) v = -INFINITY;
                sv[ni][r] = v;
            }
        }
        __builtin_amdgcn_s_setprio(0);
        #pragma unroll
        for (int r = 0; r < 4; ++r) {
            float mx = fmaxf(fmaxf(sv[0][r], sv[1][r]), fmaxf(sv[2][r], sv[3][r]));
            #pragma unroll
            for (int d = 1; d <= 8; d <<= 1) mx = fmaxf(mx, __shfl_xor(mx, d, 64));
            float mn = fmaxf(m_i[r], mx);
            float s = __expf(sv[0][r] - mn) + __expf(sv[1][r] - mn)
                    + __expf(sv[2][r] - mn) + __expf(sv[3][r] - mn);
            #pragma unroll
            for (int d = 1; d <= 8; d <<= 1) s += __shfl_xor(s, d, 64);
            l_i[r] = l_i[r] * __expf(m_i[r] - mn) + s;
            m_i[r] = mn;
        }
        __syncthreads();
        buf ^= 1;
    }

    float inv_l[4];
    #pragma unroll
    for (int r = 0; r < 4; ++r) inv_l[r] = 1.0f / l_i[r];

    // ---------------- pass 2: P write + P@V ----------------
    f32x4 o[4] = {};
    buf = 0;
    stage_k(0, 0);
    stage_v(0, 0);
    __syncthreads();
    for (int kt = 0; kt <= qt; ++kt) {
        if (kt < qt) { stage_k(kt + 1, buf ^ 1); stage_v(kt + 1, buf ^ 1); }
        const bool diag = (kt == qt);
        const short* kb = Kb[buf];
        const short* vb = Vt[buf];
        short* Psw = Ps[w];
        #pragma unroll
        for (int ni = 0; ni < 4; ++ni) {
            const int key = ni * 16 + lc;
            f32x4 acc = {};
            bf16x8 kf0 = *(const bf16x8*)&kb[key * 64 + ((quad ^ (key & 7)) << 3)];
            bf16x8 kf1 = *(const bf16x8*)&kb[key * 64 + (((quad | 4) ^ (key & 7)) << 3)];
            __builtin_amdgcn_s_setprio(1);
            acc = __builtin_amdgcn_mfma_f32_16x16x32_bf16(qf0, kf0, acc, 0, 0, 0);
            acc = __builtin_amdgcn_mfma_f32_16x16x32_bf16(qf1, kf1, acc, 0, 0, 0);
            __builtin_amdgcn_s_setprio(0);
            #pragma unroll
            for (int r = 0; r < 4; ++r) {
                float v = acc[r] * 0.125f;
                bool msk = diag && key > (qloc + r);
                float p = msk ? 0.f : __expf(v - m_i[r]) * inv_l[r];
                int prow = quad * 4 + r;
                Psw[prow * 64 + (key ^ ((prow & 7) << 3))] = f2bf(p);
            }
        }
        // P (A-layout via LDS, swizzled) @ V
        __builtin_amdgcn_s_setprio(1);
        #pragma unroll
        for (int kd = 0; kd < 2; ++kd) {
            bf16x8 pf = *(const bf16x8*)&Psw[lc * 64
                        + (((kd * 4 + quad) ^ (lc & 7)) << 3)];
            #pragma unroll
            for (int ni = 0; ni < 4; ++ni) {
                const int d = ni * 16 + lc;
                bf16x8 vf = *(const bf16x8*)&vb[d * 64
                            + (((kd * 4 + quad) ^ (d & 7)) << 3)];
                o[ni] = __builtin_amdgcn_mfma_f32_16x16x32_bf16(pf, vf, o[ni], 0, 0, 0);
            }
        }
        __builtin_amdgcn_s_setprio(0);
        // attw writeback: linear Ps row reads, un-swizzle in global column,
        // coalesced nontemporal f32x4 stores (left in flight across barrier).
        {
            const int a = lane & 7;
            #pragma unroll
            for (int wb = 0; wb < 2; ++wb) {
                const int r8 = wb * 8 + srow;
                bf16x8 pv = *(const bf16x8*)&Psw[r8 * 64 + a * 8];
                const int colc = (a ^ (r8 & 7)) << 3;
                float* dst = attw + ((size_t)bh * SEQ + qt * 64 + w * 16 + r8) * SEQ
                             + kt * 64 + colc;
                f32x4 f0 = { bf2f(pv[0]), bf2f(pv[1]), bf2f(pv[2]), bf2f(pv[3]) };
                f32x4 f1 = { bf2f(pv[4]), bf2f(pv[5]), bf2f(pv[6]), bf2f(pv[7]) };
                __builtin_nontemporal_store(f0, (f32x4*)dst);
                __builtin_nontemporal_store(f1, (f32x4*)dst + 1);
            }
        }
        // drain the 4 prefetch loads (oldest); leave the 4 NT stores in flight
        asm volatile("s_waitcnt vmcnt(4) lgkmcnt(0)" ::: "memory");
        __builtin_amdgcn_s_barrier();
        __builtin_amdgcn_sched_barrier(0);
        buf ^= 1;
    }

    // attended -> bf16 [tok][E]
    #pragma unroll
    for (int ni = 0; ni < 4; ++ni)
        #pragma unroll
        for (int r = 0; r < 4; ++r)
            attb[(size_t)(b * SEQ + qt * 64 + qloc + r) * EMBED
                 + h * 64 + ni * 16 + lc] = f2bf(o[ni][r]);

    // zero-fill strictly-upper k-tiles (k >= (qt+1)*64)
    if (qt < NT - 1) {
        const int zc4 = (qt + 1) * 16;
        for (int r = 0; r < 64; ++r) {
            f32x4* rowp = (f32x4*)(attw + ((size_t)bh * SEQ + qt * 64 + r) * SEQ);
            f32x4 z = {};
            for (int c = zc4 + tid; c < 512; c += 256)
                __builtin_nontemporal_store(z, rowp + c);
        }
    }
}

extern "C" void kernel_launch(void* const* d_in, const int* in_sizes, int n_in,
                              void* d_out, int out_size, void* d_ws, size_t ws_size,
                              hipStream_t stream)
{
    const float* x     = (const float*)d_in[0];
    const float* W_qkv = (const float*)d_in[1];
    const float* b_qkv = (const float*)d_in[2];
    const float* W_out = (const float*)d_in[3];
    const float* b_out = (const float*)d_in[4];

    float* out  = (float*)d_out;
    float* attw = out + OUT_ELEMS;

    short* xb   = (short*)d_ws;                       // 4096x1024
    short* wqt  = xb + (size_t)M_TOK * EMBED;         // 3072x1024 (W_qkv^T)
    short* wot  = wqt + (size_t)QKV_N * EMBED;        // 1024x1024 (W_out^T)
    short* qkvb = wot + (size_t)EMBED * EMBED;        // 4096x3072
    short* attb = qkvb + (size_t)M_TOK * QKV_N;       // 4096x1024
    short* Vp   = xb;  // reuse: xb is dead after GEMM1 (stream-ordered)

    cast_bf16_kernel<<<OUT_ELEMS / 4 / 256, 256, 0, stream>>>(x, xb, (int)(OUT_ELEMS / 4));
    transpose_cast_kernel<<<dim3(QKV_N / 64, EMBED / 64), 256, 0, stream>>>(W_qkv, wqt, EMBED, QKV_N);
    transpose_cast_kernel<<<dim3(EMBED / 64, EMBED / 64), 256, 0, stream>>>(W_out, wot, EMBED, EMBED);

    gemm_mfma_kernel<true><<<dim3(QKV_N / 128, M_TOK / 128), 256, 0, stream>>>(
        xb, wqt, b_qkv, qkvb, M_TOK, QKV_N, EMBED);

    pack_v_kernel<<<dim3(NT_KV, BATCH * NHEAD), 256, 0, stream>>>(qkvb, Vp);

    attn_kernel<<<dim3(NT_KV, BATCH * NHEAD), 256, 0, stream>>>(qkvb, Vp, attw, attb);

    gemm_mfma_kernel<false><<<dim3(EMBED / 128, M_TOK / 128), 256, 0, stream>>>(
        attb, wot, b_out, out, M_TOK, EMBED, EMBED);
}

// Round 4
// 772.425 us; speedup vs baseline: 1.0055x; 1.0055x over previous
//
#include <hip/hip_runtime.h>
#include <hip/hip_bf16.h>
#include <math.h>

#define BATCH 2
#define SEQ 2048
#define EMBED 1024
#define NHEAD 16
#define QKV_N 3072
#define M_TOK 4096
#define NT_KV (SEQ / 64)
#define OUT_ELEMS ((size_t)M_TOK * EMBED)

typedef __attribute__((ext_vector_type(4))) float f32x4;
typedef __attribute__((ext_vector_type(8))) short bf16x8;

__device__ __forceinline__ short f2bf(float f) {
    __hip_bfloat16 h = __float2bfloat16(f);
    return *reinterpret_cast<short*>(&h);
}
__device__ __forceinline__ float bf2f(short s) {
    union { unsigned u; float f; } c;
    c.u = ((unsigned)(unsigned short)s) << 16;
    return c.f;
}

// async global->LDS, 16B per lane; LDS dest = wave-uniform base + lane*16
__device__ __forceinline__ void gld16(const void* g, void* l) {
    __builtin_amdgcn_global_load_lds(
        (const __attribute__((address_space(1))) unsigned int*)g,
        (__attribute__((address_space(3))) unsigned int*)l, 16, 0, 0);
}

// ---------------------------------------------------------------------------
// fp32 -> bf16 cast, 4 elems/thread
// ---------------------------------------------------------------------------
__global__ __launch_bounds__(256) void cast_bf16_kernel(
    const float* __restrict__ in, short* __restrict__ out, int n4)
{
    int i = blockIdx.x * 256 + threadIdx.x;
    if (i >= n4) return;
    float4 v = ((const float4*)in)[i];
    unsigned long long pk =
        (unsigned long long)(unsigned short)f2bf(v.x)
      | ((unsigned long long)(unsigned short)f2bf(v.y) << 16)
      | ((unsigned long long)(unsigned short)f2bf(v.z) << 32)
      | ((unsigned long long)(unsigned short)f2bf(v.w) << 48);
    ((unsigned long long*)out)[i] = pk;
}

// ---------------------------------------------------------------------------
// Merged transpose+cast for BOTH weight matrices in one launch.
// in[R][C] fp32 -> out[C][R] bf16, 64x64 tiles. Blocks [0,768) do W_qkv,
// blocks [768,1024) do W_out.
// ---------------------------------------------------------------------------
__global__ __launch_bounds__(256) void transpose_cast2_kernel(
    const float* __restrict__ inA, short* __restrict__ outA,   // 1024x3072
    const float* __restrict__ inB, short* __restrict__ outB)   // 1024x1024
{
    __shared__ float t[64][65];
    const float* in; short* out; int R, C, bx, by;
    int id = blockIdx.x;
    if (id < 768) { in = inA; out = outA; R = EMBED; C = QKV_N; bx = id % 48; by = id / 48; }
    else { id -= 768; in = inB; out = outB; R = EMBED; C = EMBED; bx = id % 16; by = id / 16; }
    const int r0 = by * 64, c0 = bx * 64;
    for (int i = threadIdx.x; i < 4096; i += 256) {
        int r = i >> 6, c = i & 63;
        t[r][c] = in[(size_t)(r0 + r) * C + c0 + c];
    }
    __syncthreads();
    for (int i = threadIdx.x; i < 4096; i += 256) {
        int c = i >> 6, r = i & 63;
        out[(size_t)(c0 + c) * R + r0 + r] = f2bf(t[r][c]);
    }
}

// ---------------------------------------------------------------------------
// Pack V per head, transposed + bank-swizzle baked in:
// Vp[bh][kt][d][key'] tiles of 64x64 bf16, key' = key ^ ((d&7)<<3).
// ---------------------------------------------------------------------------
__global__ __launch_bounds__(256) void pack_v_kernel(
    const short* __restrict__ qkvb, short* __restrict__ Vp)
{
    __shared__ short tv[64][72];
    const int kt = blockIdx.x, bh = blockIdx.y;
    const int b = bh >> 4, h = bh & 15;
    const int t = threadIdx.x;
    const int row = t >> 2, cp = t & 3;
    const short* src = qkvb + (size_t)(b * SEQ + kt * 64 + row) * QKV_N
                       + 2 * EMBED + h * 64 + cp * 16;
    bf16x8 a0 = *(const bf16x8*)src;
    bf16x8 a1 = *(const bf16x8*)(src + 8);
    #pragma unroll
    for (int j = 0; j < 8; ++j) {
        tv[row][cp * 16 + j] = a0[j];
        tv[row][cp * 16 + 8 + j] = a1[j];
    }
    __syncthreads();
    const int d = row;
    short* dst = Vp + ((size_t)bh * NT_KV + kt) * 4096 + d * 64;
    bf16x8 o0, o1;
    #pragma unroll
    for (int j = 0; j < 8; ++j) {
        o0[j] = tv[cp * 16 + j][d];
        o1[j] = tv[cp * 16 + 8 + j][d];
    }
    *(bf16x8*)(dst + (((2 * cp) ^ (d & 7)) << 3)) = o0;
    *(bf16x8*)(dst + (((2 * cp + 1) ^ (d & 7)) << 3)) = o1;
}

// ---------------------------------------------------------------------------
// bf16 MFMA GEMM (m97 structure): C[M][N] = A[M][K] @ Bt[N][K]^T + bias
// ---------------------------------------------------------------------------
template <bool OUT_BF16>
__global__ __launch_bounds__(256) void gemm_mfma_kernel(
    const short* __restrict__ A, const short* __restrict__ Bt,
    const float* __restrict__ bias, void* __restrict__ C,
    int M, int N, int K)
{
    __shared__ short As[128 * 32];
    __shared__ short Bs[128 * 32];
    const int tid = threadIdx.x;
    const int w = tid >> 6, lane = tid & 63;
    const int quad = lane >> 4, lc = lane & 15;
    const int wm = w & 1, wn = w >> 1;
    const int m0 = blockIdx.y * 128, n0 = blockIdx.x * 128;

    f32x4 acc[4][4] = {};

    const int srow = (lane >> 2);
    const int schk = ((lane & 3) ^ (srow & 3)) * 8;

    for (int k0 = 0; k0 < K; k0 += 32) {
        #pragma unroll
        for (int j = 0; j < 2; ++j) {
            int r = w * 32 + j * 16 + srow;
            gld16(A + ((size_t)(m0 + r) * K + k0 + schk), &As[(w * 32 + j * 16) * 32]);
            gld16(Bt + ((size_t)(n0 + r) * K + k0 + schk), &Bs[(w * 32 + j * 16) * 32]);
        }
        __syncthreads();
        bf16x8 af[4], bf[4];
        #pragma unroll
        for (int i = 0; i < 4; ++i)
            af[i] = *(const bf16x8*)&As[(wm * 64 + i * 16 + lc) * 32
                                        + ((quad ^ (lc & 3)) << 3)];
        #pragma unroll
        for (int i = 0; i < 4; ++i)
            bf[i] = *(const bf16x8*)&Bs[(wn * 64 + i * 16 + lc) * 32
                                        + ((quad ^ (lc & 3)) << 3)];
        #pragma unroll
        for (int mi = 0; mi < 4; ++mi)
            #pragma unroll
            for (int ni = 0; ni < 4; ++ni)
                acc[mi][ni] = __builtin_amdgcn_mfma_f32_16x16x32_bf16(
                    af[mi], bf[ni], acc[mi][ni], 0, 0, 0);
        __syncthreads();
    }

    #pragma unroll
    for (int mi = 0; mi < 4; ++mi) {
        int row = m0 + wm * 64 + mi * 16 + quad * 4;
        #pragma unroll
        for (int ni = 0; ni < 4; ++ni) {
            int col = n0 + wn * 64 + ni * 16 + lc;
            float bc = bias[col];
            #pragma unroll
            for (int r = 0; r < 4; ++r) {
                float v = acc[mi][ni][r] + bc;
                if (OUT_BF16)
                    ((short*)C)[(size_t)(row + r) * N + col] = f2bf(v);
                else
                    ((float*)C)[(size_t)(row + r) * N + col] = v;
            }
        }
    }
}

// ---------------------------------------------------------------------------
// Fused causal attention, two-pass flash, v4:
//   - pass 1 uses SWAPPED QK^T: mfma(K, Q) -> D[key, q], q = lc. Same LDS
//     reads (A/B fragment layouts identical), but each lane owns one q-row's
//     stats: reduction = 15 in-lane fmax/adds + 2 shfl (d=16,32) instead of
//     32 shfl ops per iter. Stats redistributed to pass-2 layout via 8
//     one-time shfls.
//   - double-buffered K/V staging, counted vmcnt in pass 2, setprio (T4/T5).
//   - qt pairing keeps per-CU work identical; launch_bounds(256,4).
// ---------------------------------------------------------------------------
__global__ __launch_bounds__(256, 4) void attn_kernel(
    const short* __restrict__ qkvb,   // [4096][3072] bf16
    const short* __restrict__ Vp,     // [32][32][64][64] bf16, transposed+swz
    float* __restrict__ attw,         // [32][2048][2048]
    short* __restrict__ attb)         // [4096][1024] bf16
{
    const int NT = NT_KV;
    const int qt = (blockIdx.y & 8) ? (NT - 1 - (int)blockIdx.x) : (int)blockIdx.x;
    const int bh = blockIdx.y;
    const int b = bh >> 4, h = bh & 15;
    const int tid = threadIdx.x;
    const int w = tid >> 6, lane = tid & 63;
    const int quad = lane >> 4, lc = lane & 15;
    const int qloc = w * 16 + quad * 4;

    __shared__ short Kb[2][64 * 64];   // [key][d'], d' chunk-swizzled
    __shared__ short Vt[2][64 * 64];   // [d][key'], key' chunk-swizzled
    __shared__ short Ps[4][16 * 64];   // per-wave P [q][key'], swizzled

    // Q fragments, held in registers for both passes
    const short* qptr = qkvb + (size_t)(b * SEQ + qt * 64 + w * 16 + lc) * QKV_N
                        + h * 64 + quad * 8;
    const bf16x8 qf0 = *(const bf16x8*)qptr;
    const bf16x8 qf1 = *(const bf16x8*)(qptr + 32);

    const int srow = lane >> 3;                 // 0..7, row within 8-row chunk
    const int schk = ((lane & 7) ^ srow) * 8;   // swizzled source chunk

    const short* kg0 = qkvb + (size_t)(b * SEQ + w * 16 + srow) * QKV_N
                       + EMBED + h * 64 + schk;
    const size_t kstep = (size_t)64 * QKV_N;
    const short* vg0 = Vp + (size_t)bh * NT * 4096 + (w * 16) * 64 + lane * 8;

    auto stage_k = [&](int kt, int bi) {
        gld16(kg0 + (size_t)kt * kstep, &Kb[bi][(w * 16) * 64]);
        gld16(kg0 + (size_t)kt * kstep + (size_t)8 * QKV_N, &Kb[bi][(w * 16 + 8) * 64]);
    };
    auto stage_v = [&](int kt, int bi) {
        gld16(vg0 + (size_t)kt * 4096, &Vt[bi][(w * 16) * 64]);
        gld16(vg0 + (size_t)kt * 4096 + 512, &Vt[bi][(w * 16 + 8) * 64]);
    };

    // ---------------- pass 1: row max & sum (swapped QK^T) ----------------
    // This lane owns stats for q-row (w*16 + lc).
    float m_q = -INFINITY, l_q = 0.f;
    const int qrow_loc = w * 16 + lc;    // q within 64-tile, for masking

    int buf = 0;
    stage_k(0, 0);
    __syncthreads();
    for (int kt = 0; kt <= qt; ++kt) {
        if (kt < qt) stage_k(kt + 1, buf ^ 1);
        const bool diag = (kt == qt);
        const short* kb = Kb[buf];
        float sv[4][4];   // [ni][reg], key = ni*16 + quad*4 + reg
        __builtin_amdgcn_s_setprio(1);
        #pragma unroll
        for (int ni = 0; ni < 4; ++ni) {
            const int key = ni * 16 + lc;    // K fragment row (same loads as before)
            f32x4 acc = {};
            bf16x8 kf0 = *(const bf16x8*)&kb[key * 64 + ((quad ^ (key & 7)) << 3)];
            bf16x8 kf1 = *(const bf16x8*)&kb[key * 64 + (((quad | 4) ^ (key & 7)) << 3)];
            acc = __builtin_amdgcn_mfma_f32_16x16x32_bf16(kf0, qf0, acc, 0, 0, 0);
            acc = __builtin_amdgcn_mfma_f32_16x16x32_bf16(kf1, qf1, acc, 0, 0, 0);
            #pragma unroll
            for (int r = 0; r < 4; ++r) {
                float v = acc[r] * 0.125f;
                if (diag && (ni * 16 + quad * 4 + r) > qrow_loc) v = -INFINITY;
                sv[ni][r] = v;
            }
        }
        __builtin_amdgcn_s_setprio(0);
        // in-lane max over 16 keys, then cross-quad (2 shfl)
        float mx = fmaxf(fmaxf(fmaxf(sv[0][0], sv[0][1]), fmaxf(sv[0][2], sv[0][3])),
                         fmaxf(fmaxf(sv[1][0], sv[1][1]), fmaxf(sv[1][2], sv[1][3])));
        mx = fmaxf(mx, fmaxf(fmaxf(fmaxf(sv[2][0], sv[2][1]), fmaxf(sv[2][2], sv[2][3])),
                             fmaxf(fmaxf(sv[3][0], sv[3][1]), fmaxf(sv[3][2], sv[3][3]))));
        mx = fmaxf(mx, __shfl_xor(mx, 16, 64));
        mx = fmaxf(mx, __shfl_xor(mx, 32, 64));
        float mn = fmaxf(m_q, mx);
        float s = 0.f;
        #pragma unroll
        for (int ni = 0; ni < 4; ++ni)
            #pragma unroll
            for (int r = 0; r < 4; ++r)
                s += __expf(sv[ni][r] - mn);
        s += __shfl_xor(s, 16, 64);
        s += __shfl_xor(s, 32, 64);
        l_q = l_q * __expf(m_q - mn) + s;
        m_q = mn;
        __syncthreads();
        buf ^= 1;
    }

    // redistribute stats to pass-2 row layout: row r of this (w,quad) is
    // q-local = quad*4 + r, whose stats live in lane (quad*4 + r).
    float il_q = 1.0f / l_q;
    float m_i[4], inv_l[4];
    #pragma unroll
    for (int r = 0; r < 4; ++r) {
        m_i[r]   = __shfl(m_q, quad * 4 + r, 64);
        inv_l[r] = __shfl(il_q, quad * 4 + r, 64);
    }

    // ---------------- pass 2: P write + P@V ----------------
    f32x4 o[4] = {};
    buf = 0;
    stage_k(0, 0);
    stage_v(0, 0);
    __syncthreads();
    for (int kt = 0; kt <= qt; ++kt) {
        if (kt < qt) { stage_k(kt + 1, buf ^ 1); stage_v(kt + 1, buf ^ 1); }
        const bool diag = (kt == qt);
        const short* kb = Kb[buf];
        const short* vb = Vt[buf];
        short* Psw = Ps[w];
        #pragma unroll
        for (int ni = 0; ni < 4; ++ni) {
            const int key = ni * 16 + lc;
            f32x4 acc = {};
            bf16x8 kf0 = *(const bf16x8*)&kb[key * 64 + ((quad ^ (key & 7)) << 3)];
            bf16x8 kf1 = *(const bf16x8*)&kb[key * 64 + (((quad | 4) ^ (key & 7)) << 3)];
            __builtin_amdgcn_s_setprio(1);
            acc = __builtin_amdgcn_mfma_f32_16x16x32_bf16(qf0, kf0, acc, 0, 0, 0);
            acc = __builtin_amdgcn_mfma_f32_16x16x32_bf16(qf1, kf1, acc, 0, 0, 0);
            __builtin_amdgcn_s_setprio(0);
            #pragma unroll
            for (int r = 0; r < 4; ++r) {
                float v = acc[r] * 0.125f;
                bool msk = diag && key > (qloc + r);
                float p = msk ? 0.f : __expf(v - m_i[r]) * inv_l[r];
                int prow = quad * 4 + r;
                Psw[prow * 64 + (key ^ ((prow & 7) << 3))] = f2bf(p);
            }
        }
        // P (A-layout via LDS, swizzled) @ V
        __builtin_amdgcn_s_setprio(1);
        #pragma unroll
        for (int kd = 0; kd < 2; ++kd) {
            bf16x8 pf = *(const bf16x8*)&Psw[lc * 64
                        + (((kd * 4 + quad) ^ (lc & 7)) << 3)];
            #pragma unroll
            for (int ni = 0; ni < 4; ++ni) {
                const int d = ni * 16 + lc;
                bf16x8 vf = *(const bf16x8*)&vb[d * 64
                            + (((kd * 4 + quad) ^ (d & 7)) << 3)];
                o[ni] = __builtin_amdgcn_mfma_f32_16x16x32_bf16(pf, vf, o[ni], 0, 0, 0);
            }
        }
        __builtin_amdgcn_s_setprio(0);
        // attw writeback: linear Ps row reads, un-swizzle in global column,
        // coalesced nontemporal f32x4 stores (left in flight across barrier).
        {
            const int a = lane & 7;
            #pragma unroll
            for (int wb = 0; wb < 2; ++wb) {
                const int r8 = wb * 8 + srow;
                bf16x8 pv = *(const bf16x8*)&Psw[r8 * 64 + a * 8];
                const int colc = (a ^ (r8 & 7)) << 3;
                float* dst = attw + ((size_t)bh * SEQ + qt * 64 + w * 16 + r8) * SEQ
                             + kt * 64 + colc;
                f32x4 f0 = { bf2f(pv[0]), bf2f(pv[1]), bf2f(pv[2]), bf2f(pv[3]) };
                f32x4 f1 = { bf2f(pv[4]), bf2f(pv[5]), bf2f(pv[6]), bf2f(pv[7]) };
                __builtin_nontemporal_store(f0, (f32x4*)dst);
                __builtin_nontemporal_store(f1, (f32x4*)dst + 1);
            }
        }
        // drain the 4 prefetch loads (oldest); leave the 4 NT stores in flight
        asm volatile("s_waitcnt vmcnt(4) lgkmcnt(0)" ::: "memory");
        __builtin_amdgcn_s_barrier();
        __builtin_amdgcn_sched_barrier(0);
        buf ^= 1;
    }

    // attended -> bf16 [tok][E]
    #pragma unroll
    for (int ni = 0; ni < 4; ++ni)
        #pragma unroll
        for (int r = 0; r < 4; ++r)
            attb[(size_t)(b * SEQ + qt * 64 + qloc + r) * EMBED
                 + h * 64 + ni * 16 + lc] = f2bf(o[ni][r]);

    // zero-fill strictly-upper k-tiles (k >= (qt+1)*64)
    if (qt < NT - 1) {
        const int zc4 = (qt + 1) * 16;
        for (int r = 0; r < 64; ++r) {
            f32x4* rowp = (f32x4*)(attw + ((size_t)bh * SEQ + qt * 64 + r) * SEQ);
            f32x4 z = {};
            for (int c = zc4 + tid; c < 512; c += 256)
                __builtin_nontemporal_store(z, rowp + c);
        }
    }
}

extern "C" void kernel_launch(void* const* d_in, const int* in_sizes, int n_in,
                              void* d_out, int out_size, void* d_ws, size_t ws_size,
                              hipStream_t stream)
{
    const float* x     = (const float*)d_in[0];
    const float* W_qkv = (const float*)d_in[1];
    const float* b_qkv = (const float*)d_in[2];
    const float* W_out = (const float*)d_in[3];
    const float* b_out = (const float*)d_in[4];

    float* out  = (float*)d_out;
    float* attw = out + OUT_ELEMS;

    short* xb   = (short*)d_ws;                       // 4096x1024
    short* wqt  = xb + (size_t)M_TOK * EMBED;         // 3072x1024 (W_qkv^T)
    short* wot  = wqt + (size_t)QKV_N * EMBED;        // 1024x1024 (W_out^T)
    short* qkvb = wot + (size_t)EMBED * EMBED;        // 4096x3072
    short* attb = qkvb + (size_t)M_TOK * QKV_N;       // 4096x1024
    short* Vp   = xb;  // reuse: xb is dead after GEMM1 (stream-ordered)

    cast_bf16_kernel<<<OUT_ELEMS / 4 / 256, 256, 0, stream>>>(x, xb, (int)(OUT_ELEMS / 4));
    transpose_cast2_kernel<<<1024, 256, 0, stream>>>(W_qkv, wqt, W_out, wot);

    gemm_mfma_kernel<true><<<dim3(QKV_N / 128, M_TOK / 128), 256, 0, stream>>>(
        xb, wqt, b_qkv, qkvb, M_TOK, QKV_N, EMBED);

    pack_v_kernel<<<dim3(NT_KV, BATCH * NHEAD), 256, 0, stream>>>(qkvb, Vp);

    attn_kernel<<<dim3(NT_KV, BATCH * NHEAD), 256, 0, stream>>>(qkvb, Vp, attw, attb);

    gemm_mfma_kernel<false><<<dim3(EMBED / 128, M_TOK / 128), 256, 0, stream>>>(
        attb, wot, b_out, out, M_TOK, EMBED, EMBED);
}